// Round 8
// baseline (210.573 us; speedup 1.0000x reference)
//
#include <hip/hip_runtime.h>
#include <hip/hip_bf16.h>

#define VOCAB  32000
#define HIDDEN 256
#define NHASH  20
#define MROWS  4096           // 2 * 2048
#define KDIM   256
#define POOL   100000

typedef __attribute__((ext_vector_type(8))) short bf16x8;
typedef __attribute__((ext_vector_type(4))) float f32x4;

__device__ __forceinline__ unsigned short f32_bf16_rne(float f) {
  union { float f; unsigned int u; } v; v.f = f;
  unsigned int r = v.u + 0x7FFF + ((v.u >> 16) & 1);   // round-to-nearest-even
  return (unsigned short)(r >> 16);
}

__device__ __forceinline__ float bf16_f32(unsigned short u) {
  union { unsigned int u; float f; } v; v.u = (unsigned int)u << 16;
  return v.f;
}

__device__ __forceinline__ void async16(const void* g, void* l) {
  __builtin_amdgcn_global_load_lds(
      (const __attribute__((address_space(1))) unsigned int*)g,
      (__attribute__((address_space(3))) unsigned int*)l, 16, 0, 0);
}

__device__ __forceinline__ ushort4 f4_to_bf4(float4 f) {
  ushort4 o;
  o.x = f32_bf16_rne(f.x); o.y = f32_bf16_rne(f.y);
  o.z = f32_bf16_rne(f.z); o.w = f32_bf16_rne(f.w);
  return o;
}

// Streamed cast of pool + x to bf16. Grid-stride over float4s.
#define POOL_F4 (POOL * HIDDEN / 4)          // 6,400,000
#define X_F4    (MROWS * HIDDEN / 4)         // 262,144
__global__ __launch_bounds__(256)
void cast_kernel(const float* __restrict__ x, const float* __restrict__ pool,
                 unsigned short* __restrict__ xb, unsigned short* __restrict__ poolb) {
  const int step = gridDim.x * 256;
  for (int i = blockIdx.x * 256 + threadIdx.x; i < POOL_F4 + X_F4; i += step) {
    if (i < POOL_F4) {
      ((ushort4*)poolb)[i] = f4_to_bf4(((const float4*)pool)[i]);
    } else {
      const int j = i - POOL_F4;
      ((ushort4*)xb)[j] = f4_to_bf4(((const float4*)x)[j]);
    }
  }
}

// x-only cast (fallback when ws can't hold poolb)
__global__ __launch_bounds__(256)
void xcast_kernel(const float* __restrict__ x, unsigned short* __restrict__ xb) {
  const int i = blockIdx.x * 256 + threadIdx.x;   // X_F4 / 256 blocks
  ((ushort4*)xb)[i] = f4_to_bf4(((const float4*)x)[i]);
}

// Fused embed + GEMM. Grid = 500 persistent-panel blocks:
//   ntile = bid>>1 (250 ntiles x 2 blocks), each block does 16 mtiles.
// Phase 1: build B-panel [128 rows][256 k] bf16 in LDS (XOR-swizzled rows)
//          via 20 weighted 512B gathers per row (identical math to the old
//          embed kernel -> identical numerics).
// Phase 2: per mtile: stage A-tile (single-buffered, pre-swizzled source
//          global_load_lds), K-loop vs resident panel, epilogue through
//          16KB Cs overlay in 4x32-row phases with nt f32x4 stores.
// LDS = 64KB panel + 16KB Abuf/Cs = 80KB -> 2 blocks/CU.
template <bool BF16POOL>
__global__ __launch_bounds__(256)
void fused_kernel(const unsigned short* __restrict__ poolb,
                  const float* __restrict__ poolf,
                  const float* __restrict__ w, const int* __restrict__ hash,
                  const unsigned short* __restrict__ xb,
                  float* __restrict__ out) {
  __shared__ char smem[81920] __attribute__((aligned(128)));
  char*  Bp   = smem;                    // [128][512B] bf16 panel, swizzled
  short* Abuf = (short*)(smem + 65536);  // [128][64] bf16 A staging
  float* Cs   = (float*)(smem + 65536);  // overlay: [32][128] f32

  const int tid  = threadIdx.x;
  const int lane = tid & 63;
  const int wave = tid >> 6;
  const int wm   = wave >> 1;
  const int wn   = wave & 1;

  const int ntile = blockIdx.x >> 1;
  const int mhalf = blockIdx.x & 1;
  const int nbase = ntile * 128;

  // ---------- Phase 1: build B panel (wave w owns rows w*32..w*32+31) ----------
#pragma unroll 1
  for (int r = 0; r < 32; ++r) {
    const int row = wave * 32 + r;
    const int v   = nbase + row;
    int hl = 0; float wl = 0.f;
    if (lane < NHASH) {
      hl = hash[v * NHASH + lane];
      wl = w[v * NHASH + lane];
    }
    float4 a4 = make_float4(0.f, 0.f, 0.f, 0.f);
#pragma unroll
    for (int j = 0; j < NHASH; ++j) {
      const int   h  = __shfl(hl, j);
      const float ww = __shfl(wl, j);
      if (BF16POOL) {
        const ushort4 p = ((const ushort4*)(poolb + (size_t)h * HIDDEN))[lane];
        a4.x += ww * bf16_f32(p.x); a4.y += ww * bf16_f32(p.y);
        a4.z += ww * bf16_f32(p.z); a4.w += ww * bf16_f32(p.w);
      } else {
        const float4 p = ((const float4*)(poolf + (size_t)h * HIDDEN))[lane];
        a4.x += ww * p.x; a4.y += ww * p.y;
        a4.z += ww * p.z; a4.w += ww * p.w;
      }
    }
    // swizzled row write: 16B-chunk c of row r lives at byte (c<<4)^((r&7)<<4)
    *(ushort4*)(Bp + row * 512 + ((lane * 8) ^ ((row & 7) << 4))) = f4_to_bf4(a4);
  }
  __syncthreads();

  // ---------- Phase 2: 16 mtiles ----------
  // A staging: chunk c in [0,1024): row=c>>3, lds slot=c&7,
  // global colchunk = (c&7)^(row&7)  (pre-swizzled source, linear LDS dest)
  int srow[4], scol[4];
#pragma unroll
  for (int i = 0; i < 4; ++i) {
    const int c = i * 256 + tid;
    srow[i] = c >> 3;
    scol[i] = (((c & 7) ^ ((c >> 3) & 7)) << 3);
  }

  const int abase = (wm * 64 + (lane & 15)) * 128;   // bytes into Abuf
  const int brow  = wn * 64 + (lane & 15);           // panel row (+ni*16)
  const int sw    = (lane & 7) << 4;                 // XOR term (row&7 == lane&7)
  const int kq    = (lane >> 4) << 4;                // 16B k-slot in 64B k-half

#pragma unroll 1
  for (int mt = 0; mt < 16; ++mt) {
    const int mbase = (mhalf * 16 + mt) * 128;
    f32x4 acc[4][4] = {};

#pragma unroll
    for (int kt = 0; kt < 4; ++kt) {
      const int k0 = kt * 64;
#pragma unroll
      for (int i = 0; i < 4; ++i) {
        const int c = i * 256 + tid;
        async16(xb + (size_t)(mbase + srow[i]) * KDIM + k0 + scol[i], &Abuf[c * 8]);
      }
      __syncthreads();   // vmcnt drained by compiler before barrier

      const char* A = (const char*)Abuf;
#pragma unroll
      for (int kk = 0; kk < 2; ++kk) {
        const int koffA = (kk * 64 + kq) ^ sw;
        const int koffB = ((kt * 128 + kk * 64 + kq) ^ sw);
        bf16x8 a[4], b[4];
#pragma unroll
        for (int mi = 0; mi < 4; ++mi)
          a[mi] = *(const bf16x8*)(A + abase + mi * 2048 + koffA);
#pragma unroll
        for (int ni = 0; ni < 4; ++ni)
          b[ni] = *(const bf16x8*)(Bp + (brow + ni * 16) * 512 + koffB);
#pragma unroll
        for (int mi = 0; mi < 4; ++mi)
#pragma unroll
          for (int ni = 0; ni < 4; ++ni)
            acc[mi][ni] = __builtin_amdgcn_mfma_f32_16x16x32_bf16(
                a[mi], b[ni], acc[mi][ni], 0, 0, 0);
      }
      __syncthreads();   // Abuf free for next kt / epilogue overlay
    }

    // Epilogue: 4 phases of 32 rows via Cs[32][128] (overlays Abuf).
    // acc[mi][ni][j]: row = wm*64 + mi*16 + (lane>>4)*4 + j,
    //                 col = wn*64 + ni*16 + (lane&15).   (m89-verified)
#pragma unroll
    for (int p = 0; p < 4; ++p) {
      if (wm == (p >> 1)) {
        const int r0 = ((lane >> 4) << 2);
        const int c0 = wn * 64 + (lane & 15);
#pragma unroll
        for (int q = 0; q < 2; ++q) {
          const int mi = (p & 1) * 2 + q;
#pragma unroll
          for (int ni = 0; ni < 4; ++ni)
#pragma unroll
            for (int j = 0; j < 4; ++j)
              Cs[(q * 16 + r0 + j) * 128 + c0 + ni * 16] = acc[mi][ni][j];
        }
      }
      __syncthreads();
#pragma unroll
      for (int i = 0; i < 4; ++i) {
        const int flat = i * 1024 + tid * 4;   // float index in 32x128 chunk
        const int row  = flat >> 7;
        const int col  = flat & 127;
        f32x4 vv = *(const f32x4*)&Cs[row * 128 + col];
        __builtin_nontemporal_store(vv,
            (f32x4*)&out[(size_t)(mbase + p * 32 + row) * VOCAB + nbase + col]);
      }
      __syncthreads();   // Cs reads done before next phase / next mtile stage
    }
  }
}

extern "C" void kernel_launch(void* const* d_in, const int* in_sizes, int n_in,
                              void* d_out, int out_size, void* d_ws, size_t ws_size,
                              hipStream_t stream) {
  const float* x    = (const float*)d_in[0];   // [2,2048,256]
  const float* pool = (const float*)d_in[1];   // [100000,256]
  const float* imp  = (const float*)d_in[2];   // [32000,20]
  const int*   hash = (const int*)d_in[3];     // [32000,20]
  float* out = (float*)d_out;                  // [2,2048,32000]

  unsigned short* xb    = (unsigned short*)d_ws;           // 2 MB bf16 x
  unsigned short* poolb = xb + (size_t)MROWS * HIDDEN;     // 51.2 MB bf16 pool

  const size_t need = ((size_t)MROWS + POOL) * HIDDEN * 2;
  if (ws_size >= need) {
    cast_kernel<<<2048, 256, 0, stream>>>(x, pool, xb, poolb);
    fused_kernel<true><<<500, 256, 0, stream>>>(poolb, nullptr, imp, hash, xb, out);
  } else {
    xcast_kernel<<<X_F4 / 256, 256, 0, stream>>>(x, xb);
    fused_kernel<false><<<500, 256, 0, stream>>>(nullptr, pool, imp, hash, xb, out);
  }
}